// Round 4
// baseline (481.099 us; speedup 1.0000x reference)
//
#include <hip/hip_runtime.h>
#include <cstddef>

// Problem constants (reference: B=32, L=128, N=64, D=64, H=4, DH=16)
#define BB   32
#define LL   128
#define NN   64
#define DD   64
#define HH   4
#define DHH  16
#define G4   256          // 4*D gate rows
#define BPG  4            // batches per workgroup (LSTM kernels)

__device__ __forceinline__ float sigmoidf_(float x) {
    return 1.0f / (1.0f + __expf(-x));
}
__device__ __forceinline__ float tanhf_(float x) {
    // tanh(x) = 1 - 2/(exp(2x)+1); saturates correctly at +-inf
    float e = __expf(2.0f * x);
    return 1.0f - 2.0f / (e + 1.0f);
}

// ---------------------------------------------------------------------------
// Encoder: per-variable LSTM (input dim 1, hidden 64) over T=127 steps with
// online-softmax temporal attention pooling. Grid: 64 vars * 8 batchgroups.
// Thread tid owns gate row j=tid (Whh row in VGPRs); elementwise phase maps
// tid -> (j0 = tid&63, bq = tid>>6).
// ---------------------------------------------------------------------------
__global__ __launch_bounds__(256, 2)
void enc_kernel(const float* __restrict__ X,
                const float* __restrict__ Wih,
                const float* __restrict__ Whh,
                const float* __restrict__ bias,
                const float* __restrict__ poolw,
                const float* __restrict__ poolb,
                float* __restrict__ Cws)   // [B][N][D]
{
    const int n  = blockIdx.x >> 3;
    const int bg = blockIdx.x & 7;
    const int b0 = bg * BPG;
    const int tid = threadIdx.x;
    const int j0 = tid & 63;
    const int bq = tid >> 6;

    __shared__ __align__(16) float hl[64 * BPG];   // [k][b]
    __shared__ float gl[G4 * 5];                   // [j][b], pad 5 (coprime 32)
    __shared__ float xs[BPG][LL];                  // staged input series

    // Whh row j -> registers (16 x float4)
    float4 w4[16];
    const float4* wrow =
        reinterpret_cast<const float4*>(Whh + ((size_t)n * G4 + tid) * DD);
#pragma unroll
    for (int i = 0; i < 16; ++i) w4[i] = wrow[i];

    const float wih = Wih[n * G4 + tid];
    const float bj  = bias[n * G4 + tid];
    const float pwj = poolw[n * DD + j0];
    const float pbn = poolb[n];

    // stage x series for this WG's 4 batches: xs[bb][t] = X[b0+bb][t][n]
    for (int i = tid; i < BPG * LL; i += 256) {
        int bb = i >> 7, t = i & 127;
        xs[bb][t] = (t < LL - 1)
            ? X[(size_t)(b0 + bb) * (LL * NN) + (size_t)t * NN + n] : 0.0f;
    }
    hl[tid] = 0.0f;          // exactly 256 entries
    float c = 0.0f;
    float m = -1e30f, s = 0.0f, pa = 0.0f;
    __syncthreads();

    for (int t = 0; t < LL - 1; ++t) {
        // ---- gate phase: acc[b] = bj + x[b]*wih + sum_k w[k]*h[k][b] ----
        float a0 = fmaf(xs[0][t], wih, bj);
        float a1 = fmaf(xs[1][t], wih, bj);
        float a2 = fmaf(xs[2][t], wih, bj);
        float a3 = fmaf(xs[3][t], wih, bj);
#pragma unroll
        for (int k4 = 0; k4 < 16; ++k4) {
#pragma unroll
            for (int q = 0; q < 4; ++q) {
                const float4 h4 =
                    *reinterpret_cast<const float4*>(&hl[(k4 * 4 + q) * 4]);
                const float wk = (q == 0) ? w4[k4].x : (q == 1) ? w4[k4].y
                               : (q == 2) ? w4[k4].z : w4[k4].w;
                a0 = fmaf(wk, h4.x, a0);
                a1 = fmaf(wk, h4.y, a1);
                a2 = fmaf(wk, h4.z, a2);
                a3 = fmaf(wk, h4.w, a3);
            }
        }
        {
            float* g = &gl[tid * 5];
            g[0] = a0; g[1] = a1; g[2] = a2; g[3] = a3;
        }
        __syncthreads();

        // ---- elementwise phase: thread (j0, bq) ----
        const float gi = gl[(j0      ) * 5 + bq];
        const float gf = gl[(j0 +  64) * 5 + bq];
        const float gg = gl[(j0 + 128) * 5 + bq];
        const float go = gl[(j0 + 192) * 5 + bq];
        c = sigmoidf_(gf) * c + sigmoidf_(gi) * tanhf_(gg);
        const float h = sigmoidf_(go) * tanhf_(c);

        // ---- pooling score: full-wave reduce of h*pw over j0 ----
        float p = h * pwj;
#pragma unroll
        for (int off = 32; off >= 1; off >>= 1) p += __shfl_xor(p, off, 64);
        const float score = p + pbn;

        // online softmax update (uniform within wave)
        const float mn   = fmaxf(m, score);
        const float corr = __expf(m - mn);
        const float wgt  = __expf(score - mn);
        s  = s * corr + wgt;
        pa = pa * corr + wgt * h;
        m  = mn;

        hl[j0 * 4 + bq] = h;
        __syncthreads();
    }

    // C[b0+bq][n][j0] = pa / s
    Cws[(size_t)(b0 + bq) * (NN * DD) + (size_t)n * DD + j0] = pa / s;
}

// ---------------------------------------------------------------------------
// Attention per (b, h): qkv slice -> scores -> softmax -> o head slice.
// All LDS arrays odd-padded (<=2-way conflicts). Tiny kernel (~84 MFLOP total).
// ---------------------------------------------------------------------------
__global__ __launch_bounds__(256)
void attn_kernel(const float* __restrict__ Cws,
                 const float* __restrict__ Wqkv,
                 const float* __restrict__ bqkv,
                 float* __restrict__ Ows)   // [B][N][D], pre-projection
{
    const int b = blockIdx.x >> 2;
    const int h = blockIdx.x & 3;
    const int tid = threadIdx.x;

    __shared__ float Cl[64][65];
    __shared__ float Wl[48][65];      // rows: 0-15 q, 16-31 k, 32-47 v
    __shared__ float biasl[48];
    __shared__ float ql[64][17], kl[64][17], vl[64][17];
    __shared__ float sl[64][65];

    for (int i = tid; i < 64 * 64; i += 256)
        Cl[i >> 6][i & 63] = Cws[(size_t)b * (NN * DD) + i];
    for (int i = tid; i < 48 * 64; i += 256) {
        int row = i >> 6, col = i & 63;
        int grp = row >> 4, r = row & 15;
        Wl[row][col] = Wqkv[(size_t)(grp * 64 + h * 16 + r) * DD + col];
    }
    if (tid < 48) {
        int grp = tid >> 4, r = tid & 15;
        biasl[tid] = bqkv[grp * 64 + h * 16 + r];
    }
    __syncthreads();

    // qkv: 3*64*16 outputs
    for (int i = tid; i < 3 * 64 * 16; i += 256) {
        int sec = i >> 10;
        int rem = i & 1023;
        int nn = rem >> 4, dh = rem & 15;
        float acc = biasl[sec * 16 + dh];
        const float* wr = &Wl[sec * 16 + dh][0];
#pragma unroll 16
        for (int k = 0; k < 64; ++k) acc = fmaf(Cl[nn][k], wr[k], acc);
        if      (sec == 0) ql[nn][dh] = acc;
        else if (sec == 1) kl[nn][dh] = acc;
        else               vl[nn][dh] = acc;
    }
    __syncthreads();

    // scores s[n][m] = (q[n] . k[m]) / 4
    for (int i = tid; i < 64 * 64; i += 256) {
        int nn = i >> 6, mm = i & 63;
        float acc = 0.0f;
#pragma unroll
        for (int d = 0; d < 16; ++d) acc = fmaf(ql[nn][d], kl[mm][d], acc);
        sl[nn][mm] = acc * 0.25f;
    }
    __syncthreads();

    // row softmax (64 rows, 1 thread each — tiny)
    if (tid < 64) {
        float mx = -1e30f;
        for (int mm = 0; mm < 64; ++mm) mx = fmaxf(mx, sl[tid][mm]);
        float ss = 0.0f;
        for (int mm = 0; mm < 64; ++mm) {
            float e = __expf(sl[tid][mm] - mx);
            sl[tid][mm] = e;
            ss += e;
        }
        float inv = 1.0f / ss;
        for (int mm = 0; mm < 64; ++mm) sl[tid][mm] *= inv;
    }
    __syncthreads();

    // o[n][dh] = sum_m p[n][m] * v[m][dh]
    for (int i = tid; i < 64 * 16; i += 256) {
        int nn = i >> 4, dh = i & 15;
        float acc = 0.0f;
#pragma unroll 16
        for (int mm = 0; mm < 64; ++mm) acc = fmaf(sl[nn][mm], vl[mm][dh], acc);
        Ows[(size_t)b * (NN * DD) + (size_t)nn * DD + h * 16 + dh] = acc;
    }
}

// ---------------------------------------------------------------------------
// Output projection: C_star = O @ Wo^T + bo  (written straight into d_out)
// ---------------------------------------------------------------------------
__global__ __launch_bounds__(256)
void proj_kernel(const float* __restrict__ Ows,
                 const float* __restrict__ Wo,
                 const float* __restrict__ bo,
                 float* __restrict__ Cstar)  // [B][N][D] region of d_out
{
    const int b = blockIdx.x;
    const int tid = threadIdx.x;
    __shared__ float Ol[64][65];
    __shared__ float Wl[64][65];

    for (int i = tid; i < 64 * 64; i += 256) {
        Ol[i >> 6][i & 63] = Ows[(size_t)b * (NN * DD) + i];
        Wl[i >> 6][i & 63] = Wo[i];
    }
    __syncthreads();

    for (int i = tid; i < 64 * 64; i += 256) {
        int nn = i >> 6, d = i & 63;
        float acc = bo[d];
#pragma unroll 16
        for (int k = 0; k < 64; ++k) acc = fmaf(Ol[nn][k], Wl[d][k], acc);
        Cstar[(size_t)b * (NN * DD) + i] = acc;
    }
}

// ---------------------------------------------------------------------------
// Decoder: per-variable LSTM with zero inputs, h0/c0 = tanh(Cs W^T + b),
// per-step output y = h . ow + ob written to recon/pred.
// ---------------------------------------------------------------------------
__global__ __launch_bounds__(256, 2)
void dec_kernel(const float* __restrict__ Whh,
                const float* __restrict__ bias,
                const float* __restrict__ WhI,
                const float* __restrict__ bhI,
                const float* __restrict__ WcI,
                const float* __restrict__ bcI,
                const float* __restrict__ ow,
                const float* __restrict__ ob,
                const float* __restrict__ Cstar,  // [B][N][D] (in d_out)
                float* __restrict__ recon,        // [B][L-1][N]
                float* __restrict__ pred)         // [B][N]
{
    const int n  = blockIdx.x >> 3;
    const int bg = blockIdx.x & 7;
    const int b0 = bg * BPG;
    const int tid = threadIdx.x;
    const int j0 = tid & 63;
    const int bq = tid >> 6;

    __shared__ __align__(16) float hl[64 * BPG];   // [k][b]
    __shared__ float gl[G4 * 5];
    __shared__ float csl[BPG][64];

    float4 w4[16];
    const float4* wrow =
        reinterpret_cast<const float4*>(Whh + ((size_t)n * G4 + tid) * DD);
#pragma unroll
    for (int i = 0; i < 16; ++i) w4[i] = wrow[i];
    const float bj  = bias[n * G4 + tid];
    const float owj = ow[n * DD + j0];
    const float obn = ob[n];

    // stage C_star rows for this WG's batches
    {
        int bb = tid >> 6, d = tid & 63;
        csl[bb][d] = Cstar[(size_t)(b0 + bb) * (NN * DD) + (size_t)n * DD + d];
    }
    __syncthreads();

    // h0 = tanh(cs . WhI[j0] + bh), c0 = tanh(cs . WcI[j0] + bc) for (j0,bq)
    float ah = bhI[n * DD + j0];
    float ac = bcI[n * DD + j0];
    {
        const float4* whr =
            reinterpret_cast<const float4*>(WhI + ((size_t)n * DD + j0) * DD);
        const float4* wcr =
            reinterpret_cast<const float4*>(WcI + ((size_t)n * DD + j0) * DD);
#pragma unroll
        for (int i = 0; i < 16; ++i) {
            float4 wh = whr[i], wc = wcr[i];
            ah = fmaf(wh.x, csl[bq][i * 4 + 0], ah);
            ah = fmaf(wh.y, csl[bq][i * 4 + 1], ah);
            ah = fmaf(wh.z, csl[bq][i * 4 + 2], ah);
            ah = fmaf(wh.w, csl[bq][i * 4 + 3], ah);
            ac = fmaf(wc.x, csl[bq][i * 4 + 0], ac);
            ac = fmaf(wc.y, csl[bq][i * 4 + 1], ac);
            ac = fmaf(wc.z, csl[bq][i * 4 + 2], ac);
            ac = fmaf(wc.w, csl[bq][i * 4 + 3], ac);
        }
    }
    float c = tanhf_(ac);
    hl[j0 * 4 + bq] = tanhf_(ah);
    __syncthreads();

    for (int t = 0; t < LL; ++t) {
        // gate phase (x = 0): acc[b] = bj + sum_k w[k]*h[k][b]
        float a0 = bj, a1 = bj, a2 = bj, a3 = bj;
#pragma unroll
        for (int k4 = 0; k4 < 16; ++k4) {
#pragma unroll
            for (int q = 0; q < 4; ++q) {
                const float4 h4 =
                    *reinterpret_cast<const float4*>(&hl[(k4 * 4 + q) * 4]);
                const float wk = (q == 0) ? w4[k4].x : (q == 1) ? w4[k4].y
                               : (q == 2) ? w4[k4].z : w4[k4].w;
                a0 = fmaf(wk, h4.x, a0);
                a1 = fmaf(wk, h4.y, a1);
                a2 = fmaf(wk, h4.z, a2);
                a3 = fmaf(wk, h4.w, a3);
            }
        }
        {
            float* g = &gl[tid * 5];
            g[0] = a0; g[1] = a1; g[2] = a2; g[3] = a3;
        }
        __syncthreads();

        const float gi = gl[(j0      ) * 5 + bq];
        const float gf = gl[(j0 +  64) * 5 + bq];
        const float gg = gl[(j0 + 128) * 5 + bq];
        const float go = gl[(j0 + 192) * 5 + bq];
        c = sigmoidf_(gf) * c + sigmoidf_(gi) * tanhf_(gg);
        const float h = sigmoidf_(go) * tanhf_(c);

        // y[t][b] = h . ow + ob  (full-wave reduce over j0)
        float p = h * owj;
#pragma unroll
        for (int off = 32; off >= 1; off >>= 1) p += __shfl_xor(p, off, 64);
        if (j0 == 0) {
            const float y = p + obn;
            const int b = b0 + bq;
            if (t < LL - 1)
                recon[(size_t)b * ((LL - 1) * NN) + (size_t)t * NN + n] = y;
            else
                pred[(size_t)b * NN + n] = y;
        }

        hl[j0 * 4 + bq] = h;
        __syncthreads();
    }
}

extern "C" void kernel_launch(void* const* d_in, const int* in_sizes, int n_in,
                              void* d_out, int out_size, void* d_ws, size_t ws_size,
                              hipStream_t stream) {
    (void)in_sizes; (void)n_in; (void)out_size; (void)ws_size;

    const float* X         = (const float*)d_in[0];
    const float* enc_Wih   = (const float*)d_in[1];
    const float* enc_Whh   = (const float*)d_in[2];
    const float* enc_b     = (const float*)d_in[3];
    const float* pool_w    = (const float*)d_in[4];
    const float* pool_b    = (const float*)d_in[5];
    const float* attn_Wqkv = (const float*)d_in[6];
    const float* attn_bqkv = (const float*)d_in[7];
    const float* attn_Wo   = (const float*)d_in[8];
    const float* attn_bo   = (const float*)d_in[9];
    // d_in[10] = dec_Wih: multiplied by all-zero inputs in the reference -> unused
    const float* dec_Whh   = (const float*)d_in[11];
    const float* dec_b     = (const float*)d_in[12];
    const float* init_h_W  = (const float*)d_in[13];
    const float* init_h_b  = (const float*)d_in[14];
    const float* init_c_W  = (const float*)d_in[15];
    const float* init_c_b  = (const float*)d_in[16];
    const float* out_w     = (const float*)d_in[17];
    const float* out_b     = (const float*)d_in[18];

    float* out   = (float*)d_out;
    float* recon = out;                                     // B*(L-1)*N = 260096
    float* pred  = out + (size_t)BB * (LL - 1) * NN;        // B*N       = 2048
    float* cstar = pred + (size_t)BB * NN;                  // B*N*D     = 131072

    float* Cws = (float*)d_ws;                              // [B][N][D]
    float* Ows = Cws + (size_t)BB * NN * DD;                // [B][N][D]

    enc_kernel<<<dim3(NN * 8), dim3(256), 0, stream>>>(
        X, enc_Wih, enc_Whh, enc_b, pool_w, pool_b, Cws);

    attn_kernel<<<dim3(BB * HH), dim3(256), 0, stream>>>(
        Cws, attn_Wqkv, attn_bqkv, Ows);

    proj_kernel<<<dim3(BB), dim3(256), 0, stream>>>(
        Ows, attn_Wo, attn_bo, cstar);

    dec_kernel<<<dim3(NN * 8), dim3(256), 0, stream>>>(
        dec_Whh, dec_b, init_h_W, init_h_b, init_c_W, init_c_b,
        out_w, out_b, cstar, recon, pred);
}